// Round 2
// baseline (361.101 us; speedup 1.0000x reference)
//
#include <hip/hip_runtime.h>

typedef __bf16 bf16;
typedef __bf16 bf16x8 __attribute__((ext_vector_type(8)));
typedef float floatx4 __attribute__((ext_vector_type(4)));

#define MFMA16(a, b, c) __builtin_amdgcn_mfma_f32_16x16x32_bf16((a), (b), (c), 0, 0, 0)

// async global->LDS, 16B per lane. LDS side is wave-uniform base (lane0) + lane*16.
__device__ __forceinline__ void gl2lds16(const bf16* g, bf16* l) {
  __builtin_amdgcn_global_load_lds(
      (const __attribute__((address_space(1))) void*)g,
      (__attribute__((address_space(3))) void*)l, 16, 0, 0);
}
// wait vmcnt(0) only (lgkm=15, exp=7 left open)
__device__ __forceinline__ void wait_vm0() { __builtin_amdgcn_s_waitcnt(0x0f70); }

// ---------------------------------------------------------------------------
// fp32 -> bf16 ingest: x | wq | wk | wv | wo, 8 elems/thread.
// Segment boundaries in 8-elem groups: 524288 | 524288 | 131072 | 131072 | 524288
// ---------------------------------------------------------------------------
__device__ __forceinline__ void cvt8(const float* __restrict__ s,
                                     bf16* __restrict__ d, int i8) {
  const float4 a = ((const float4*)s)[i8 * 2];
  const float4 b = ((const float4*)s)[i8 * 2 + 1];
  bf16x8 o;
  o[0] = (bf16)a.x; o[1] = (bf16)a.y; o[2] = (bf16)a.z; o[3] = (bf16)a.w;
  o[4] = (bf16)b.x; o[5] = (bf16)b.y; o[6] = (bf16)b.z; o[7] = (bf16)b.w;
  *(bf16x8*)(d + i8 * 8) = o;
}

__global__ __launch_bounds__(256) void convert_kernel(
    const float* __restrict__ x, const float* __restrict__ wq,
    const float* __restrict__ wk, const float* __restrict__ wv,
    const float* __restrict__ wo, bf16* __restrict__ xb,
    bf16* __restrict__ wqb, bf16* __restrict__ wkb, bf16* __restrict__ wvb,
    bf16* __restrict__ wob) {
  const int g = blockIdx.x * 256 + threadIdx.x;
  if (g < 524288) cvt8(x, xb, g);
  else if (g < 1048576) cvt8(wq, wqb, g - 524288);
  else if (g < 1179648) cvt8(wk, wkb, g - 1048576);
  else if (g < 1310720) cvt8(wv, wvb, g - 1179648);
  else cvt8(wo, wob, g - 1310720);
}

// ---------------------------------------------------------------------------
// Shared 128x128x(K) GEMM tile body:  C[r][c] = sum_k A[r][k] * B[c][k]
// Fragment-ordered LDS: slot mt (0..7) holds rows mt*16..mt*16+15 of the
// 32-wide k-panel at slot_base + lane*16B (conflict-free ds_read_b128 and
// legal global_load_lds lane order).
// ---------------------------------------------------------------------------
template <typename OutT>
__device__ __forceinline__ void gemm_tile_body(
    const bf16* __restrict__ A, int lda,
    const bf16* __restrict__ B, int ldb,
    OutT* __restrict__ C, int ldc, int K,
    bf16* As, bf16* Bs) {
  const int t = threadIdx.x;
  const int w = t >> 6, lane = t & 63;
  const int l15 = lane & 15, qd = lane >> 4;
  const int wr = w >> 1, wc = w & 1;

  floatx4 acc[4][4];
#pragma unroll
  for (int i = 0; i < 4; ++i)
#pragma unroll
    for (int j = 0; j < 4; ++j) acc[i][j] = (floatx4){0.f, 0.f, 0.f, 0.f};

  // staging: wave w fills slots w and w+4 for both A and B
  const int mt0 = w, mt1 = w + 4;
  const int kseg = qd * 8;
  const bf16* ga0 = A + (mt0 * 16 + l15) * lda + kseg;
  const bf16* ga1 = A + (mt1 * 16 + l15) * lda + kseg;
  const bf16* gb0 = B + (mt0 * 16 + l15) * ldb + kseg;
  const bf16* gb1 = B + (mt1 * 16 + l15) * ldb + kseg;
  bf16* lA0 = As + mt0 * 512 + lane * 8;
  bf16* lA1 = As + mt1 * 512 + lane * 8;
  bf16* lB0 = Bs + mt0 * 512 + lane * 8;
  bf16* lB1 = Bs + mt1 * 512 + lane * 8;

  for (int k0 = 0; k0 < K; k0 += 32) {
    gl2lds16(ga0 + k0, lA0);
    gl2lds16(ga1 + k0, lA1);
    gl2lds16(gb0 + k0, lB0);
    gl2lds16(gb1 + k0, lB1);
    wait_vm0();
    __syncthreads();

    bf16x8 a[4], b[4];
#pragma unroll
    for (int i = 0; i < 4; ++i)
      a[i] = *(const bf16x8*)(As + (wr * 4 + i) * 512 + lane * 8);
#pragma unroll
    for (int j = 0; j < 4; ++j)
      b[j] = *(const bf16x8*)(Bs + (wc * 4 + j) * 512 + lane * 8);
#pragma unroll
    for (int i = 0; i < 4; ++i)
#pragma unroll
      for (int j = 0; j < 4; ++j) acc[i][j] = MFMA16(a[i], b[j], acc[i][j]);
    __syncthreads();
  }

  // epilogue: C/D layout col=lane&15, row=quad*4+reg
#pragma unroll
  for (int i = 0; i < 4; ++i)
#pragma unroll
    for (int j = 0; j < 4; ++j) {
      const int row = wr * 64 + i * 16 + qd * 4;
      const int col = wc * 64 + j * 16 + l15;
#pragma unroll
      for (int r = 0; r < 4; ++r)
        C[(row + r) * ldc + col] = (OutT)acc[i][j][r];
    }
}

// ---------------------------------------------------------------------------
// Fused QKV projection: X(2048x2048) @ [Wq|Wk|Wv]^T
// grid (24, 16): nblk 0..15 -> Q, 16..19 -> K, 20..23 -> V
// ---------------------------------------------------------------------------
__global__ __launch_bounds__(256) void gemm_qkv(
    const bf16* __restrict__ x, const bf16* __restrict__ wq,
    const bf16* __restrict__ wk, const bf16* __restrict__ wv,
    bf16* __restrict__ Qws, bf16* __restrict__ Kws, bf16* __restrict__ Vws) {
  __shared__ bf16 As[4096], Bs[4096];
  const int m0 = blockIdx.y * 128;
  const int nb = blockIdx.x;
  const bf16* B;
  bf16* C;
  int ldc;
  if (nb < 16) {
    B = wq + nb * 128 * 2048;
    C = Qws + m0 * 2048 + nb * 128;
    ldc = 2048;
  } else if (nb < 20) {
    B = wk + (nb - 16) * 128 * 2048;
    C = Kws + m0 * 512 + (nb - 16) * 128;
    ldc = 512;
  } else {
    B = wv + (nb - 20) * 128 * 2048;
    C = Vws + m0 * 512 + (nb - 20) * 128;
    ldc = 512;
  }
  gemm_tile_body<bf16>(x + m0 * 2048, 2048, B, 2048, C, ldc, 2048, As, Bs);
}

// ---------------------------------------------------------------------------
// Output projection: O(2048x2048) @ Wo^T -> d_out[0:4194304] (fp32)
// ---------------------------------------------------------------------------
__global__ __launch_bounds__(256) void gemm_o(
    const bf16* __restrict__ Ows, const bf16* __restrict__ wo,
    float* __restrict__ out) {
  __shared__ bf16 As[4096], Bs[4096];
  const int m0 = blockIdx.y * 128, n0 = blockIdx.x * 128;
  gemm_tile_body<float>(Ows + m0 * 2048, 2048, wo + n0 * 2048, 2048,
                        out + m0 * 2048 + n0, 2048, 2048, As, Bs);
}

// ---------------------------------------------------------------------------
// RoPE on Q (in place, bf16), RoPE on K (in place bf16 + fp32 GQA-repeat to
// d_out), V repeat to d_out (fp32), and V^T [kvh][d][L] (bf16) for flash.
// Thread space: Q pairs 2097152 | K pairs 524288 | V-out 131072 | V^T 131072
// ---------------------------------------------------------------------------
__global__ __launch_bounds__(256) void rope_repeat_kernel(
    bf16* __restrict__ Qws, bf16* __restrict__ Kws,
    const bf16* __restrict__ Vws, bf16* __restrict__ Vt,
    float* __restrict__ kout, float* __restrict__ vout) {
  const int gid = blockIdx.x * 256 + threadIdx.x;
  const float NEG_LOG2_10000_D32 = -0.4152410118609203f;  // -log2(10000)/32
  if (gid < 2097152) {  // Q: l = gid>>10, pair index pr in 0..1023 (h*32+a)
    const int l = gid >> 10, pr = gid & 1023, a = pr & 31;
    bf16* p = Qws + l * 2048 + pr * 2;
    const float x0 = (float)p[0], x1 = (float)p[1];
    const float ang = (float)(l + 1) * exp2f(NEG_LOG2_10000_D32 * (float)a);
    float s, c;
    __sincosf(ang, &s, &c);
    p[0] = (bf16)(c * x0 - s * x1);
    p[1] = (bf16)(s * x0 + c * x1);
  } else if (gid < 2097152 + 524288) {  // K pairs
    const int g = gid - 2097152;
    const int l = g >> 8, pr = g & 255, a = pr & 31, kvh = pr >> 5;
    bf16* p = Kws + l * 512 + pr * 2;
    const float x0 = (float)p[0], x1 = (float)p[1];
    const float ang = (float)(l + 1) * exp2f(NEG_LOG2_10000_D32 * (float)a);
    float s, c;
    __sincosf(ang, &s, &c);
    const float y0 = c * x0 - s * x1;
    const float y1 = s * x0 + c * x1;
    p[0] = (bf16)y0;
    p[1] = (bf16)y1;
#pragma unroll
    for (int rep = 0; rep < 4; ++rep) {
      float* o = kout + (((kvh * 4 + rep) * 2048 + l) * 64 + a * 2);
      o[0] = y0;
      o[1] = y1;
    }
  } else if (gid < 2097152 + 524288 + 131072) {  // V repeat to d_out (fp32)
    const int c = gid - (2097152 + 524288);
    const int l = c >> 6, seg = c & 63, kvh = seg >> 3;
    const bf16x8 v = *(const bf16x8*)(Vws + l * 512 + seg * 8);
    float4 f0, f1;
    f0.x = (float)v[0]; f0.y = (float)v[1]; f0.z = (float)v[2]; f0.w = (float)v[3];
    f1.x = (float)v[4]; f1.y = (float)v[5]; f1.z = (float)v[6]; f1.w = (float)v[7];
#pragma unroll
    for (int rep = 0; rep < 4; ++rep) {
      float* o = vout + (((kvh * 4 + rep) * 2048 + l) * 64 + (seg & 7) * 8);
      *(float4*)o = f0;
      *(float4*)(o + 4) = f1;
    }
  } else {  // V^T build: Vt[kvh][d][l] (bf16)
    const int c = gid - (2097152 + 524288 + 131072);
    const int kvh = c >> 14, r2 = c & 16383, dseg = r2 >> 11, l = r2 & 2047;
    const int d0 = dseg * 8;
    const bf16x8 v = *(const bf16x8*)(Vws + l * 512 + kvh * 64 + d0);
#pragma unroll
    for (int jj = 0; jj < 8; ++jj)
      Vt[kvh * 131072 + (d0 + jj) * 2048 + l] = v[jj];
  }
}

// ---------------------------------------------------------------------------
// Flash attention: grid (32 qtiles [reversed], 32 heads), 256 threads.
// Wave w owns q rows q0+16w..+15. K/V staged per 64-key tile in
// fragment-ordered LDS via global_load_lds; P round-trips through per-wave
// fragment-ordered LDS (C/D -> A layout transform).
// ---------------------------------------------------------------------------
__global__ __launch_bounds__(256) void flash_kernel(
    const bf16* __restrict__ Qws, const bf16* __restrict__ Kws,
    const bf16* __restrict__ Vt, bf16* __restrict__ Ows) {
  __shared__ bf16 Ks[8 * 512];        // slot (j*2+ks): K[key=j*16+l15][ks*32+qd*8+..]
  __shared__ bf16 Vs[8 * 512];        // slot (j'*2+ks): V^T[dim=j'*16+l15][ks*32+qd*8+..]
  __shared__ bf16 Ps[4][2][64][8];    // per-wave P in A-fragment order

  const int qt = 31 - (int)blockIdx.x;  // longest blocks dispatch first
  const int h = blockIdx.y;
  const int kh = h >> 2;  // GQA: interleaved repeat -> kv head = h/4
  const int q0 = qt * 64;
  const int t = threadIdx.x, w = t >> 6, lane = t & 63;
  const int l15 = lane & 15, qd = lane >> 4;

  // Q fragments (rows q0+16w+l15), k-dim split in two 32-chunks
  const bf16* qrow = Qws + (q0 + 16 * w + l15) * 2048 + h * 64;
  const bf16x8 aq0 = *(const bf16x8*)(qrow + qd * 8);
  const bf16x8 aq1 = *(const bf16x8*)(qrow + 32 + qd * 8);

  floatx4 o[4] = {};
  float mrun[4] = {-1e30f, -1e30f, -1e30f, -1e30f};
  float lrun[4] = {};

  // staging: wave w fills slots w and w+4 (for K and for V^T)
  const int s0 = w, s1 = w + 4;
  const bf16* gK0 = Kws + ((s0 >> 1) * 16 + l15) * 512 + kh * 64 + (s0 & 1) * 32 + qd * 8;
  const bf16* gK1 = Kws + ((s1 >> 1) * 16 + l15) * 512 + kh * 64 + (s1 & 1) * 32 + qd * 8;
  const bf16* gV0 = Vt + kh * 131072 + ((s0 >> 1) * 16 + l15) * 2048 + (s0 & 1) * 32 + qd * 8;
  const bf16* gV1 = Vt + kh * 131072 + ((s1 >> 1) * 16 + l15) * 2048 + (s1 & 1) * 32 + qd * 8;
  bf16* lK0 = &Ks[s0 * 512 + lane * 8];
  bf16* lK1 = &Ks[s1 * 512 + lane * 8];
  bf16* lV0 = &Vs[s0 * 512 + lane * 8];
  bf16* lV1 = &Vs[s1 * 512 + lane * 8];

  for (int kt = 0; kt <= qt; ++kt) {
    const int kt64 = kt * 64;
    gl2lds16(gK0 + kt64 * 512, lK0);
    gl2lds16(gK1 + kt64 * 512, lK1);
    gl2lds16(gV0 + kt64, lV0);
    gl2lds16(gV1 + kt64, lV1);
    wait_vm0();
    __syncthreads();

    // S = Q K^T  (4 n-tiles of 16 keys)
    floatx4 s4[4];
#pragma unroll
    for (int j = 0; j < 4; ++j) {
      const bf16x8 b0 = *(const bf16x8*)&Ks[(j * 2 + 0) * 512 + lane * 8];
      const bf16x8 b1 = *(const bf16x8*)&Ks[(j * 2 + 1) * 512 + lane * 8];
      floatx4 z = {};
      z = MFMA16(aq0, b0, z);
      z = MFMA16(aq1, b1, z);
      s4[j] = z;
    }
    // scale + causal mask (only diagonal tile needs it)
#pragma unroll
    for (int j = 0; j < 4; ++j)
#pragma unroll
      for (int r = 0; r < 4; ++r) s4[j][r] *= 0.125f;
    if (kt == qt) {
      const int rowq = q0 + 16 * w + qd * 4;
#pragma unroll
      for (int j = 0; j < 4; ++j) {
        const int key = kt64 + j * 16 + l15;
#pragma unroll
        for (int r = 0; r < 4; ++r)
          if (key > rowq + r) s4[j][r] = -1e30f;
      }
    }
    // row max across the 16 lanes holding each row
    float mx[4] = {-1e30f, -1e30f, -1e30f, -1e30f};
#pragma unroll
    for (int j = 0; j < 4; ++j)
#pragma unroll
      for (int r = 0; r < 4; ++r) mx[r] = fmaxf(mx[r], s4[j][r]);
#pragma unroll
    for (int msk = 1; msk <= 8; msk <<= 1)
#pragma unroll
      for (int r = 0; r < 4; ++r) mx[r] = fmaxf(mx[r], __shfl_xor(mx[r], msk));

    float al[4];
#pragma unroll
    for (int r = 0; r < 4; ++r) {
      const float mn = fmaxf(mrun[r], mx[r]);
      al[r] = __expf(mrun[r] - mn);
      mrun[r] = mn;
    }
    float rs[4];
#pragma unroll
    for (int r = 0; r < 4; ++r) {
      float acc = 0.f;
#pragma unroll
      for (int j = 0; j < 4; ++j) {
        const float p = __expf(s4[j][r] - mrun[r]);
        s4[j][r] = p;
        acc += p;
      }
      rs[r] = acc;
    }
#pragma unroll
    for (int msk = 1; msk <= 8; msk <<= 1)
#pragma unroll
      for (int r = 0; r < 4; ++r) rs[r] += __shfl_xor(rs[r], msk);
#pragma unroll
    for (int r = 0; r < 4; ++r) lrun[r] = lrun[r] * al[r] + rs[r];
#pragma unroll
    for (int j = 0; j < 4; ++j)
#pragma unroll
      for (int r = 0; r < 4; ++r) o[j][r] *= al[r];

    // P: C/D layout -> A-fragment layout via per-wave LDS buffer
#pragma unroll
    for (int j = 0; j < 4; ++j) {
      const int k = j * 16 + l15;
      const int laneP = ((k >> 3) & 3) * 16 + qd * 4;
#pragma unroll
      for (int r = 0; r < 4; ++r)
        Ps[w][k >> 5][laneP + r][k & 7] = (bf16)s4[j][r];
    }
    // O += P V
#pragma unroll
    for (int ks = 0; ks < 2; ++ks) {
      const bf16x8 ap = *(const bf16x8*)&Ps[w][ks][lane][0];
#pragma unroll
      for (int j = 0; j < 4; ++j)
        o[j] = MFMA16(ap, *(const bf16x8*)&Vs[(j * 2 + ks) * 512 + lane * 8], o[j]);
    }
    __syncthreads();  // protect Ks/Vs before next tile's staging
  }

  // normalize + store
  float inv[4];
#pragma unroll
  for (int r = 0; r < 4; ++r) inv[r] = 1.0f / lrun[r];
#pragma unroll
  for (int j = 0; j < 4; ++j) {
    const int row = q0 + 16 * w + qd * 4;
    const int col = h * 64 + j * 16 + l15;
#pragma unroll
    for (int r = 0; r < 4; ++r)
      Ows[(row + r) * 2048 + col] = (bf16)(o[j][r] * inv[r]);
  }
}

// ---------------------------------------------------------------------------
extern "C" void kernel_launch(void* const* d_in, const int* in_sizes, int n_in,
                              void* d_out, int out_size, void* d_ws,
                              size_t ws_size, hipStream_t stream) {
  const float* x = (const float*)d_in[0];
  // d_in[1] = mask: causality is recomputed in-kernel, unused.
  const float* wq = (const float*)d_in[2];
  const float* wk = (const float*)d_in[3];
  const float* wv = (const float*)d_in[4];
  const float* wo = (const float*)d_in[5];

  float* out = (float*)d_out;            // (2048, 2048) fp32
  float* kout = out + 4194304;           // (32, 2048, 64) fp32
  float* vout = out + 8388608;           // (32, 2048, 64) fp32

  bf16* ws = (bf16*)d_ws;
  bf16* xb = ws;                         // 2048 x 2048
  bf16* wqb = xb + 4194304;              // 2048 x 2048
  bf16* wkb = wqb + 4194304;             // 512 x 2048
  bf16* wvb = wkb + 1048576;             // 512 x 2048
  bf16* wob = wvb + 1048576;             // 2048 x 2048
  bf16* Qws = wob + 4194304;             // 2048 x 2048
  bf16* Kws = Qws + 4194304;             // 2048 x 512
  bf16* Vws = Kws + 1048576;             // 2048 x 512
  bf16* Vt = Vws + 1048576;              // 8 x 64 x 2048 (V^T per kv head)
  bf16* Ows = Vt + 1048576;              // 2048 x 2048 (attention out)

  convert_kernel<<<dim3(7168), dim3(256), 0, stream>>>(x, wq, wk, wv, wo, xb,
                                                       wqb, wkb, wvb, wob);
  gemm_qkv<<<dim3(24, 16), dim3(256), 0, stream>>>(xb, wqb, wkb, wvb, Qws, Kws,
                                                   Vws);
  rope_repeat_kernel<<<dim3(11264), dim3(256), 0, stream>>>(Qws, Kws, Vws, Vt,
                                                            kout, vout);
  flash_kernel<<<dim3(32, 32), dim3(256), 0, stream>>>(Qws, Kws, Vt, Ows);
  gemm_o<<<dim3(16, 16), dim3(256), 0, stream>>>(Ows, wob, out);
}

// Round 4
// 314.575 us; speedup vs baseline: 1.1479x; 1.1479x over previous
//
#include <hip/hip_runtime.h>

typedef __bf16 bf16;
typedef __bf16 bf16x8 __attribute__((ext_vector_type(8)));
typedef float floatx4 __attribute__((ext_vector_type(4)));
typedef float floatx16 __attribute__((ext_vector_type(16)));
typedef unsigned int uint;

#define MFMA16(a, b, c) __builtin_amdgcn_mfma_f32_16x16x32_bf16((a), (b), (c), 0, 0, 0)
#define MFMA32(a, b, c) __builtin_amdgcn_mfma_f32_32x32x16_bf16((a), (b), (c), 0, 0, 0)

// async global->LDS, 16B per lane. LDS side is wave-uniform base (lane0) + lane*16.
__device__ __forceinline__ void gl2lds16(const bf16* g, bf16* l) {
  __builtin_amdgcn_global_load_lds(
      (const __attribute__((address_space(1))) void*)g,
      (__attribute__((address_space(3))) void*)l, 16, 0, 0);
}
// wait vmcnt(0) only (lgkm=15, exp=7 left open)
__device__ __forceinline__ void wait_vm0() { __builtin_amdgcn_s_waitcnt(0x0f70); }

// ---------------------------------------------------------------------------
// fp32 -> bf16 ingest: x | wq | wk | wv | wo, 8 elems/thread.
// ---------------------------------------------------------------------------
__device__ __forceinline__ void cvt8(const float* __restrict__ s,
                                     bf16* __restrict__ d, int i8) {
  const float4 a = ((const float4*)s)[i8 * 2];
  const float4 b = ((const float4*)s)[i8 * 2 + 1];
  bf16x8 o;
  o[0] = (bf16)a.x; o[1] = (bf16)a.y; o[2] = (bf16)a.z; o[3] = (bf16)a.w;
  o[4] = (bf16)b.x; o[5] = (bf16)b.y; o[6] = (bf16)b.z; o[7] = (bf16)b.w;
  *(bf16x8*)(d + i8 * 8) = o;
}

__global__ __launch_bounds__(256) void convert_kernel(
    const float* __restrict__ x, const float* __restrict__ wq,
    const float* __restrict__ wk, const float* __restrict__ wv,
    const float* __restrict__ wo, bf16* __restrict__ xb,
    bf16* __restrict__ wqb, bf16* __restrict__ wkb, bf16* __restrict__ wvb,
    bf16* __restrict__ wob) {
  const int g = blockIdx.x * 256 + threadIdx.x;
  if (g < 524288) cvt8(x, xb, g);
  else if (g < 1048576) cvt8(wq, wqb, g - 524288);
  else if (g < 1179648) cvt8(wk, wkb, g - 1048576);
  else if (g < 1310720) cvt8(wv, wvb, g - 1179648);
  else cvt8(wo, wob, g - 1310720);
}

// ---------------------------------------------------------------------------
// Shared 128x128x(K) GEMM tile body (fragment-ordered LDS, m97 structure).
// ---------------------------------------------------------------------------
template <typename OutT>
__device__ __forceinline__ void gemm_tile_body(
    const bf16* __restrict__ A, int lda,
    const bf16* __restrict__ B, int ldb,
    OutT* __restrict__ C, int ldc, int K,
    bf16* As, bf16* Bs) {
  const int t = threadIdx.x;
  const int w = t >> 6, lane = t & 63;
  const int l15 = lane & 15, qd = lane >> 4;
  const int wr = w >> 1, wc = w & 1;

  floatx4 acc[4][4];
#pragma unroll
  for (int i = 0; i < 4; ++i)
#pragma unroll
    for (int j = 0; j < 4; ++j) acc[i][j] = (floatx4){0.f, 0.f, 0.f, 0.f};

  const int mt0 = w, mt1 = w + 4;
  const int kseg = qd * 8;
  const bf16* ga0 = A + (mt0 * 16 + l15) * lda + kseg;
  const bf16* ga1 = A + (mt1 * 16 + l15) * lda + kseg;
  const bf16* gb0 = B + (mt0 * 16 + l15) * ldb + kseg;
  const bf16* gb1 = B + (mt1 * 16 + l15) * ldb + kseg;
  bf16* lA0 = As + mt0 * 512 + lane * 8;
  bf16* lA1 = As + mt1 * 512 + lane * 8;
  bf16* lB0 = Bs + mt0 * 512 + lane * 8;
  bf16* lB1 = Bs + mt1 * 512 + lane * 8;

  for (int k0 = 0; k0 < K; k0 += 32) {
    gl2lds16(ga0 + k0, lA0);
    gl2lds16(ga1 + k0, lA1);
    gl2lds16(gb0 + k0, lB0);
    gl2lds16(gb1 + k0, lB1);
    wait_vm0();
    __syncthreads();

    bf16x8 a[4], b[4];
#pragma unroll
    for (int i = 0; i < 4; ++i)
      a[i] = *(const bf16x8*)(As + (wr * 4 + i) * 512 + lane * 8);
#pragma unroll
    for (int j = 0; j < 4; ++j)
      b[j] = *(const bf16x8*)(Bs + (wc * 4 + j) * 512 + lane * 8);
#pragma unroll
    for (int i = 0; i < 4; ++i)
#pragma unroll
      for (int j = 0; j < 4; ++j) acc[i][j] = MFMA16(a[i], b[j], acc[i][j]);
    __syncthreads();
  }

#pragma unroll
  for (int i = 0; i < 4; ++i)
#pragma unroll
    for (int j = 0; j < 4; ++j) {
      const int row = wr * 64 + i * 16 + qd * 4;
      const int col = wc * 64 + j * 16 + l15;
#pragma unroll
      for (int r = 0; r < 4; ++r)
        C[(row + r) * ldc + col] = (OutT)acc[i][j][r];
    }
}

// ---------------------------------------------------------------------------
// Fused QKV projection: X(2048x2048) @ [Wq|Wk|Wv]^T
// ---------------------------------------------------------------------------
__global__ __launch_bounds__(256) void gemm_qkv(
    const bf16* __restrict__ x, const bf16* __restrict__ wq,
    const bf16* __restrict__ wk, const bf16* __restrict__ wv,
    bf16* __restrict__ Qws, bf16* __restrict__ Kws, bf16* __restrict__ Vws) {
  __shared__ bf16 As[4096], Bs[4096];
  const int m0 = blockIdx.y * 128;
  const int nb = blockIdx.x;
  const bf16* B;
  bf16* C;
  int ldc;
  if (nb < 16) {
    B = wq + nb * 128 * 2048;
    C = Qws + m0 * 2048 + nb * 128;
    ldc = 2048;
  } else if (nb < 20) {
    B = wk + (nb - 16) * 128 * 2048;
    C = Kws + m0 * 512 + (nb - 16) * 128;
    ldc = 512;
  } else {
    B = wv + (nb - 20) * 128 * 2048;
    C = Vws + m0 * 512 + (nb - 20) * 128;
    ldc = 512;
  }
  gemm_tile_body<bf16>(x + m0 * 2048, 2048, B, 2048, C, ldc, 2048, As, Bs);
}

// ---------------------------------------------------------------------------
// Output projection: O(2048x2048) @ Wo^T -> d_out[0:4194304] (fp32)
// ---------------------------------------------------------------------------
__global__ __launch_bounds__(256) void gemm_o(
    const bf16* __restrict__ Ows, const bf16* __restrict__ wo,
    float* __restrict__ out) {
  __shared__ bf16 As[4096], Bs[4096];
  const int m0 = blockIdx.y * 128, n0 = blockIdx.x * 128;
  gemm_tile_body<float>(Ows + m0 * 2048, 2048, wo + n0 * 2048, 2048,
                        out + m0 * 2048 + n0, 2048, 2048, As, Bs);
}

// ---------------------------------------------------------------------------
// RoPE Q (in place), RoPE K (in place + per-head Kh[kvh][l][64] + fp32 repeat
// to d_out), V repeat to d_out (fp32), V^T [kvh][d][L] (bf16) for flash.
// ---------------------------------------------------------------------------
__global__ __launch_bounds__(256) void rope_repeat_kernel(
    bf16* __restrict__ Qws, bf16* __restrict__ Kws, bf16* __restrict__ Kh,
    const bf16* __restrict__ Vws, bf16* __restrict__ Vt,
    float* __restrict__ kout, float* __restrict__ vout) {
  const int gid = blockIdx.x * 256 + threadIdx.x;
  const float NEG_LOG2_10000_D32 = -0.4152410118609203f;  // -log2(10000)/32
  if (gid < 2097152) {  // Q pairs
    const int l = gid >> 10, pr = gid & 1023, a = pr & 31;
    bf16* p = Qws + l * 2048 + pr * 2;
    const float x0 = (float)p[0], x1 = (float)p[1];
    const float ang = (float)(l + 1) * exp2f(NEG_LOG2_10000_D32 * (float)a);
    float s, c;
    __sincosf(ang, &s, &c);
    p[0] = (bf16)(c * x0 - s * x1);
    p[1] = (bf16)(s * x0 + c * x1);
  } else if (gid < 2097152 + 524288) {  // K pairs
    const int g = gid - 2097152;
    const int l = g >> 8, pr = g & 255, a = pr & 31, kvh = pr >> 5;
    bf16* p = Kws + l * 512 + pr * 2;
    const float x0 = (float)p[0], x1 = (float)p[1];
    const float ang = (float)(l + 1) * exp2f(NEG_LOG2_10000_D32 * (float)a);
    float s, c;
    __sincosf(ang, &s, &c);
    const float y0 = c * x0 - s * x1;
    const float y1 = s * x0 + c * x1;
    p[0] = (bf16)y0;
    p[1] = (bf16)y1;
    bf16* kp = Kh + (kvh * 2048 + l) * 64 + a * 2;
    kp[0] = (bf16)y0;
    kp[1] = (bf16)y1;
#pragma unroll
    for (int rep = 0; rep < 4; ++rep) {
      float* o = kout + (((kvh * 4 + rep) * 2048 + l) * 64 + a * 2);
      o[0] = y0;
      o[1] = y1;
    }
  } else if (gid < 2097152 + 524288 + 131072) {  // V repeat to d_out (fp32)
    const int c = gid - (2097152 + 524288);
    const int l = c >> 6, seg = c & 63, kvh = seg >> 3;
    const bf16x8 v = *(const bf16x8*)(Vws + l * 512 + seg * 8);
    float4 f0, f1;
    f0.x = (float)v[0]; f0.y = (float)v[1]; f0.z = (float)v[2]; f0.w = (float)v[3];
    f1.x = (float)v[4]; f1.y = (float)v[5]; f1.z = (float)v[6]; f1.w = (float)v[7];
#pragma unroll
    for (int rep = 0; rep < 4; ++rep) {
      float* o = vout + (((kvh * 4 + rep) * 2048 + l) * 64 + (seg & 7) * 8);
      *(float4*)o = f0;
      *(float4*)(o + 4) = f1;
    }
  } else {  // V^T build: Vt[kvh][d][l] (bf16)
    const int c = gid - (2097152 + 524288 + 131072);
    const int kvh = c >> 14, r2 = c & 16383, dseg = r2 >> 11, l = r2 & 2047;
    const int d0 = dseg * 8;
    const bf16x8 v = *(const bf16x8*)(Vws + l * 512 + kvh * 64 + d0);
#pragma unroll
    for (int jj = 0; jj < 8; ++jj)
      Vt[kvh * 131072 + (d0 + jj) * 2048 + l] = v[jj];
  }
}

// ---------------------------------------------------------------------------
// Flash attention v3: 32x32x16 MFMA, S^T = K.Q^T and O^T = V^T.P^T so the
// lane-scalar online-softmax state (one q-row per lane, q = qw + (lane&31))
// is consistent across BOTH matmuls. P transform is a register half-exchange
// (shfl_xor 32); A/B fragment-layout symmetry means staged K/V data and
// exchanged P registers serve either operand role unchanged.
// grid (16, 32); 128 q-rows/block (4 waves x 32); double-buffered staging.
// ---------------------------------------------------------------------------
__global__ __launch_bounds__(256) void flash_kernel(
    const bf16* __restrict__ Qws, const bf16* __restrict__ Kh,
    const bf16* __restrict__ Vt, bf16* __restrict__ Ows) {
  __shared__ bf16 KVs[2][2][4096];  // [buf][K=0 / V=1][8 slots * 512]
  __shared__ bf16 Osh[128 * 66];    // epilogue transpose, stride 66 (bank-free)

  const int h = blockIdx.y;
  const int qt = ((h >> 4) & 1) ? (int)blockIdx.x : 15 - (int)blockIdx.x;
  const int kh = h >> 2;  // GQA interleaved repeat
  const int q0 = qt * 128;
  const int t = threadIdx.x, w = t >> 6, lane = t & 63;
  const int l31 = lane & 31, hf = lane >> 5;
  const int qw = q0 + w * 32;  // wave's q base; lane's q = qw + l31

  // Q B-fragments: B[k=d][n=q], lane (l31,hf) holds Q[qw+l31][c*16+hf*8+j]
  bf16x8 qf[4];
  {
    const bf16* qrow = Qws + (qw + l31) * 2048 + h * 64 + hf * 8;
#pragma unroll
    for (int c = 0; c < 4; ++c) qf[c] = *(const bf16x8*)(qrow + c * 16);
  }

  floatx16 o[2] = {};  // O^T[m=d' tile n][n=q]: col = q = l31 (lane-owned)
  float mrun = -3e38f, lrun = 0.f;

  // staging: wave w stages K slots {w, w+4} and V slots {w, w+4}
  // K slot s (tt=s>>2, c=s&3): lane <- Kh[kh][kt64 + tt*32 + l31][c*16+hf*8..]
  // V slot s (n=s>>2, c=s&3):  lane <- Vt[kh][n*32 + l31][kt64 + c*16+hf*8..]
  const int s0 = w, s1 = w + 4;
  const bf16* gK0 = Kh + kh * 131072 + ((s0 >> 2) * 32 + l31) * 64 + (s0 & 3) * 16 + hf * 8;
  const bf16* gK1 = Kh + kh * 131072 + ((s1 >> 2) * 32 + l31) * 64 + (s1 & 3) * 16 + hf * 8;
  const bf16* gV0 = Vt + kh * 131072 + ((s0 >> 2) * 32 + l31) * 2048 + (s0 & 3) * 16 + hf * 8;
  const bf16* gV1 = Vt + kh * 131072 + ((s1 >> 2) * 32 + l31) * 2048 + (s1 & 3) * 16 + hf * 8;

  const int nkt = 2 * qt + 2;
  // prologue: stage kt=0 into buf 0
  gl2lds16(gK0, &KVs[0][0][s0 * 512 + lane * 8]);
  gl2lds16(gK1, &KVs[0][0][s1 * 512 + lane * 8]);
  gl2lds16(gV0, &KVs[0][1][s0 * 512 + lane * 8]);
  gl2lds16(gV1, &KVs[0][1][s1 * 512 + lane * 8]);

  const float C = 0.1803368801f;  // 0.125 * log2(e)
  for (int kt = 0; kt < nkt; ++kt) {
    wait_vm0();
    __syncthreads();
    if (kt + 1 < nkt) {  // prefetch next tile into other buffer
      const int nb = (kt + 1) & 1;
      const int koff = (kt + 1) * 4096, voff = (kt + 1) * 64;
      gl2lds16(gK0 + koff, &KVs[nb][0][s0 * 512 + lane * 8]);
      gl2lds16(gK1 + koff, &KVs[nb][0][s1 * 512 + lane * 8]);
      gl2lds16(gV0 + voff, &KVs[nb][1][s0 * 512 + lane * 8]);
      gl2lds16(gV1 + voff, &KVs[nb][1][s1 * 512 + lane * 8]);
    }
    const int kt64 = kt * 64;
    if (kt64 > qw + 31) continue;  // fully masked for this wave
    const bf16* Kb = &KVs[kt & 1][0][0];
    const bf16* Vb = &KVs[kt & 1][1][0];

    // S^T = K . Q^T : two 32-key tiles; C/D col = q, row = key local
    floatx16 st[2];
#pragma unroll
    for (int tt = 0; tt < 2; ++tt) {
      floatx16 z = {};
#pragma unroll
      for (int c = 0; c < 4; ++c) {
        const bf16x8 kf = *(const bf16x8*)(Kb + (tt * 4 + c) * 512 + lane * 8);
        z = MFMA32(kf, qf[c], z);
      }
      st[tt] = z;
    }
    // causal mask (diagonal region only); key = kt64+tt*32+(r&3)+8*(r>>2)+4*hf
    if (kt64 + 64 > qw) {
      const int myq = qw + l31;
#pragma unroll
      for (int tt = 0; tt < 2; ++tt)
#pragma unroll
        for (int r = 0; r < 16; ++r) {
          const int key = kt64 + tt * 32 + (r & 3) + 8 * (r >> 2) + 4 * hf;
          if (key > myq) st[tt][r] = -1e30f;
        }
    }
    // online softmax: lane-scalar m/l; reduce across hf halves (lane ^ 32)
    float mx = -3e38f;
#pragma unroll
    for (int tt = 0; tt < 2; ++tt)
#pragma unroll
      for (int r = 0; r < 16; ++r) mx = fmaxf(mx, st[tt][r]);
    mx = fmaxf(mx, __shfl_xor(mx, 32));
    const float mn = fmaxf(mrun, mx);
    const float al = __builtin_amdgcn_exp2f((mrun - mn) * C);
    mrun = mn;
    float rs = 0.f;
#pragma unroll
    for (int tt = 0; tt < 2; ++tt)
#pragma unroll
      for (int r = 0; r < 16; ++r) {
        const float p = __builtin_amdgcn_exp2f((st[tt][r] - mn) * C);
        st[tt][r] = p;
        rs += p;
      }
    rs += __shfl_xor(rs, 32);
    lrun = lrun * al + rs;
    // rescale O^T: col = q = lane-owned -> al is the right factor for ALL regs
#pragma unroll
    for (int n = 0; n < 2; ++n)
#pragma unroll
      for (int r = 0; r < 16; ++r) o[n][r] *= al;

    // P^T B-frags from S^T C/D via half-exchange (owner hf = j>>2):
    // pk[tt][g][p] packs keys m = 8g + 4*hf + 2p + {0,1} (consecutive dword)
    uint pk[2][4][2];
#pragma unroll
    for (int tt = 0; tt < 2; ++tt)
#pragma unroll
      for (int g = 0; g < 4; ++g)
#pragma unroll
        for (int p = 0; p < 2; ++p) {
          union { bf16 h2[2]; uint u; } cv;
          cv.h2[0] = (bf16)st[tt][4 * g + 2 * p];
          cv.h2[1] = (bf16)st[tt][4 * g + 2 * p + 1];
          pk[tt][g][p] = cv.u;
        }
    uint own_[2][2][2], rv[2][2][2];
#pragma unroll
    for (int tt = 0; tt < 2; ++tt)
#pragma unroll
      for (int gam = 0; gam < 2; ++gam)
#pragma unroll
        for (int p = 0; p < 2; ++p) {
          own_[tt][gam][p] = hf ? pk[tt][2 * gam + 1][p] : pk[tt][2 * gam][p];
          const uint snd = hf ? pk[tt][2 * gam][p] : pk[tt][2 * gam + 1][p];
          rv[tt][gam][p] = (uint)__shfl_xor((int)snd, 32);
        }
    // chunk c = tt*2+gam covers keys [c*16, c*16+16); dwords 0,1 from hf=0 owner
#pragma unroll
    for (int c = 0; c < 4; ++c) {
      const int tt = c >> 1, gam = c & 1;
      union { uint u[4]; bf16x8 v; } pf;
      pf.u[0] = hf ? rv[tt][gam][0] : own_[tt][gam][0];
      pf.u[1] = hf ? rv[tt][gam][1] : own_[tt][gam][1];
      pf.u[2] = hf ? own_[tt][gam][0] : rv[tt][gam][0];
      pf.u[3] = hf ? own_[tt][gam][1] : rv[tt][gam][1];
      // O^T = V^T . P^T : A = V chunk (m = d'), B = P^T chunk (n = q)
#pragma unroll
      for (int n = 0; n < 2; ++n)
        o[n] = MFMA32(*(const bf16x8*)(Vb + (n * 4 + c) * 512 + lane * 8),
                      pf.v, o[n]);
    }
  }

  // epilogue: O^T C/D -> LDS transpose -> coalesced row-major store.
  // lane holds O[q = qw+l31][d' = n*32 + (r&3)+8*(r>>2)+4*hf]
  const float inv = 1.f / lrun;
#pragma unroll
  for (int n = 0; n < 2; ++n)
#pragma unroll
    for (int r = 0; r < 16; ++r) {
      const int dl = n * 32 + (r & 3) + 8 * (r >> 2) + 4 * hf;
      Osh[(w * 32 + l31) * 66 + dl] = (bf16)(o[n][r] * inv);
    }
  __syncthreads();
#pragma unroll
  for (int i = 0; i < 4; ++i) {
    const int row = (t >> 3) + i * 32;
    const int col = (t & 7) * 8;
    const bf16x8 vv = *(const bf16x8*)&Osh[row * 66 + col];
    *(bf16x8*)&Ows[(q0 + row) * 2048 + h * 64 + col] = vv;
  }
}

// ---------------------------------------------------------------------------
extern "C" void kernel_launch(void* const* d_in, const int* in_sizes, int n_in,
                              void* d_out, int out_size, void* d_ws,
                              size_t ws_size, hipStream_t stream) {
  const float* x = (const float*)d_in[0];
  // d_in[1] = mask: causality recomputed in-kernel, unused.
  const float* wq = (const float*)d_in[2];
  const float* wk = (const float*)d_in[3];
  const float* wv = (const float*)d_in[4];
  const float* wo = (const float*)d_in[5];

  float* out = (float*)d_out;            // (2048, 2048) fp32
  float* kout = out + 4194304;           // (32, 2048, 64) fp32
  float* vout = out + 8388608;           // (32, 2048, 64) fp32

  bf16* ws = (bf16*)d_ws;
  bf16* xb = ws;                         // 2048 x 2048
  bf16* wqb = xb + 4194304;              // 2048 x 2048
  bf16* wkb = wqb + 4194304;             // 512 x 2048
  bf16* wvb = wkb + 1048576;             // 512 x 2048
  bf16* wob = wvb + 1048576;             // 2048 x 2048
  bf16* Qws = wob + 4194304;             // 2048 x 2048
  bf16* Kws = Qws + 4194304;             // 2048 x 512
  bf16* Vws = Kws + 1048576;             // 2048 x 512
  bf16* Vt = Vws + 1048576;              // 8 x 64 x 2048 (V^T per kv head)
  bf16* Ows = Vt + 1048576;              // 2048 x 2048 (attention out)
  bf16* Kh = Ows + 4194304;              // 8 x 2048 x 64 (roped K per kv head)

  convert_kernel<<<dim3(7168), dim3(256), 0, stream>>>(x, wq, wk, wv, wo, xb,
                                                       wqb, wkb, wvb, wob);
  gemm_qkv<<<dim3(24, 16), dim3(256), 0, stream>>>(xb, wqb, wkb, wvb, Qws, Kws,
                                                   Vws);
  rope_repeat_kernel<<<dim3(11264), dim3(256), 0, stream>>>(Qws, Kws, Kh, Vws,
                                                            Vt, kout, vout);
  flash_kernel<<<dim3(16, 32), dim3(256), 0, stream>>>(Qws, Kh, Vt, Ows);
  gemm_o<<<dim3(16, 16), dim3(256), 0, stream>>>(Ows, wob, out);
}